// Round 1
// baseline (1005.813 us; speedup 1.0000x reference)
//
#include <hip/hip_runtime.h>
#include <cstdint>

typedef __bf16 bf16_t;
typedef __attribute__((ext_vector_type(8))) __bf16 bf16x8;
typedef __attribute__((ext_vector_type(4))) __bf16 bf16x4;
typedef __attribute__((ext_vector_type(4))) float f32x4;

typedef __attribute__((address_space(1))) void void_g;
typedef __attribute__((address_space(3))) void void_l;

#define GLDS16(gp, lp) __builtin_amdgcn_global_load_lds( \
    (void_g*)(uintptr_t)(gp), (void_l*)(uintptr_t)(lp), 16, 0, 0)

constexpr int Bc = 4, Sc = 1024, Hc = 32, KVHc = 8, HDc = 128, DMc = 4096;
constexpr int NQ = 6144;     // q|k|v concatenated width
constexpr int WINc = 512;

// ---------------- cast hidden fp32 -> bf16 (vectorized) ----------------
__global__ void cast_kernel(const float* __restrict__ in, bf16_t* __restrict__ out, int n4) {
    int i = blockIdx.x * blockDim.x + threadIdx.x;
    if (i >= n4) return;
    float4 v = reinterpret_cast<const float4*>(in)[i];
    bf16x4 o;
    o[0] = (bf16_t)v.x; o[1] = (bf16_t)v.y; o[2] = (bf16_t)v.z; o[3] = (bf16_t)v.w;
    reinterpret_cast<bf16x4*>(out)[i] = o;
}

// ---------------- cast+transpose: in fp32 [R][C] -> out bf16 [C][R] ----------------
__global__ void transpose_cast(const float* __restrict__ in, bf16_t* __restrict__ out,
                               int R, int C) {
    __shared__ float tile[32][33];
    int c0 = blockIdx.x * 32, r0 = blockIdx.y * 32;
    int tx = threadIdx.x, ty = threadIdx.y;   // (32,8)
    for (int i = 0; i < 32; i += 8)
        tile[ty + i][tx] = in[(size_t)(r0 + ty + i) * C + c0 + tx];
    __syncthreads();
    for (int i = 0; i < 32; i += 8)
        out[(size_t)(c0 + ty + i) * R + r0 + tx] = (bf16_t)tile[tx][ty + i];
}

// ---------------- bf16 MFMA GEMM: C[M][N] = A[M][K] * BT[N][K]^T ----------------
// m97 structure: 128x128 tile, BK=32, global_load_lds width-16 staging.
template <typename CT>
__global__ __launch_bounds__(256) void gemm_bt(const bf16_t* __restrict__ A,
                                               const bf16_t* __restrict__ BT,
                                               CT* __restrict__ C,
                                               int M, int N, int K) {
    __shared__ bf16_t As[128 * 32];
    __shared__ bf16_t Bs[128 * 32];
    const int t = threadIdx.x;
    const int lane = t & 63, wave = t >> 6;
    const int wr = wave >> 1, wc = wave & 1;
    const int l15 = lane & 15, quad = lane >> 4;
    const int mBase = blockIdx.y * 128, nBase = blockIdx.x * 128;

    const int srow = t >> 2;           // 0..63
    const int scol = (t & 3) * 8;      // 0,8,16,24
    const bf16_t* Ag = A + (size_t)(mBase + srow) * K + scol;
    const bf16_t* Bg = BT + (size_t)(nBase + srow) * K + scol;
    bf16_t* ldsA = &As[wave * 512];    // elements; lane deposits at +lane*16B
    bf16_t* ldsB = &Bs[wave * 512];

    f32x4 acc[4][4] = {};

    for (int kk = 0; kk < K; kk += 32) {
        GLDS16(Ag + kk,                  ldsA);
        GLDS16(Ag + kk + (size_t)64 * K, ldsA + 2048);
        GLDS16(Bg + kk,                  ldsB);
        GLDS16(Bg + kk + (size_t)64 * K, ldsB + 2048);
        __syncthreads();
        bf16x8 af[4], bfv[4];
#pragma unroll
        for (int i = 0; i < 4; i++)
            af[i] = *reinterpret_cast<const bf16x8*>(&As[(wr * 64 + i * 16 + l15) * 32 + quad * 8]);
#pragma unroll
        for (int j = 0; j < 4; j++)
            bfv[j] = *reinterpret_cast<const bf16x8*>(&Bs[(wc * 64 + j * 16 + l15) * 32 + quad * 8]);
#pragma unroll
        for (int i = 0; i < 4; i++)
#pragma unroll
            for (int j = 0; j < 4; j++)
                acc[i][j] = __builtin_amdgcn_mfma_f32_16x16x32_bf16(af[i], bfv[j], acc[i][j], 0, 0, 0);
        __syncthreads();
    }
    // epilogue: C/D layout col=lane&15, row=quad*4+reg
#pragma unroll
    for (int i = 0; i < 4; i++) {
        int row0 = mBase + wr * 64 + i * 16 + quad * 4;
#pragma unroll
        for (int j = 0; j < 4; j++) {
            int col = nBase + wc * 64 + j * 16 + l15;
#pragma unroll
            for (int r = 0; r < 4; r++)
                C[(size_t)(row0 + r) * N + col] = (CT)acc[i][j][r];
        }
    }
}

// ---------------- RoPE: qkv bf16 [4096][6144] -> Qo [4096][4096], Ko [4096][1024] ----------------
__global__ void rope_kernel(const bf16_t* __restrict__ qkv, const int* __restrict__ pos,
                            bf16_t* __restrict__ Qo, bf16_t* __restrict__ Ko) {
    int t = blockIdx.y;
    int hd = blockIdx.x * blockDim.x + threadIdx.x;  // 0..2559 (40 heads x 64 pairs)
    int head = hd >> 6, d = hd & 63;
    float p = (float)pos[t];
    // inv_freq[d] = 1e6^(-d/64);  log2(1e6) = 19.931568569324174
    float invf = exp2f(-(float)d * (19.931568569324174f / 64.0f));
    float ang = p * invf;
    float cs = cosf(ang), sn = sinf(ang);
    const bf16_t* src; bf16_t* dst;
    if (head < 32) {
        src = qkv + (size_t)t * NQ + head * 128 + d;
        dst = Qo + (size_t)t * DMc + head * 128 + d;
    } else {
        int kh = head - 32;
        src = qkv + (size_t)t * NQ + 4096 + kh * 128 + d;
        dst = Ko + (size_t)t * (KVHc * HDc) + kh * 128 + d;
    }
    float x1 = (float)src[0], x2 = (float)src[64];
    dst[0]  = (bf16_t)(x1 * cs - x2 * sn);
    dst[64] = (bf16_t)(x2 * cs + x1 * sn);
}

// ---------------- V transpose: qkv v-part -> Vt [b*KVH][HD][S] ----------------
__global__ void vtrans_kernel(const bf16_t* __restrict__ qkv, bf16_t* __restrict__ Vt) {
    __shared__ bf16_t tile[32][33];
    int bh = blockIdx.z;               // b*8+kvh
    int b = bh >> 3, kvh = bh & 7;
    int s0 = blockIdx.x * 32, d0 = blockIdx.y * 32;
    int tx = threadIdx.x, ty = threadIdx.y;  // (32,8)
    for (int i = 0; i < 32; i += 8)
        tile[ty + i][tx] = qkv[(size_t)(b * Sc + s0 + ty + i) * NQ + 5120 + kvh * 128 + d0 + tx];
    __syncthreads();
    for (int i = 0; i < 32; i += 8)
        Vt[((size_t)bh * 128 + d0 + ty + i) * Sc + s0 + tx] = tile[tx][ty + i];
}

// ---------------- attention: flash-style, one wave per (b, h, 16-query tile) ----------------
__global__ __launch_bounds__(64) void attn_kernel(const bf16_t* __restrict__ Q,
                                                  const bf16_t* __restrict__ Kk,
                                                  const bf16_t* __restrict__ Vt,
                                                  bf16_t* __restrict__ O) {
    __shared__ bf16_t Plds[16 * 32];
    int bid = blockIdx.x;
    int qt = bid & 63;
    int h = (bid >> 6) & 31;
    int b = bid >> 11;
    int kvh = h >> 2;
    int lane = threadIdx.x;
    int l15 = lane & 15, quad = lane >> 4;
    int qb = qt * 16;

    // Q fragments: A-layout A[m=l15][k=quad*8+j], 4 chunks of K=32 dims
    bf16x8 qf[4];
    const bf16_t* qp = Q + (size_t)(b * Sc + qb + l15) * DMc + h * HDc + quad * 8;
#pragma unroll
    for (int c = 0; c < 4; c++) qf[c] = *reinterpret_cast<const bf16x8*>(qp + c * 32);

    f32x4 oacc[8] = {};
    float m_r[4], l_r[4];
#pragma unroll
    for (int r = 0; r < 4; r++) { m_r[r] = -1e30f; l_r[r] = 0.f; }

    const bf16_t* kbase = Kk + (size_t)b * Sc * (KVHc * HDc) + kvh * HDc + quad * 8;
    const bf16_t* vbase = Vt + (size_t)(b * KVHc + kvh) * HDc * Sc;

    int lo = qb - (WINc - 1); if (lo < 0) lo = 0;
    int kv_lo = lo & ~31;
    for (int kv = kv_lo; kv < qb + 16; kv += 32) {
        // QK^T for 32 keys (two 16-key chunks); B-layout lane = key, contiguous dims
        f32x4 s0 = {}, s1 = {};
        const bf16_t* k0 = kbase + (size_t)(kv + l15) * (KVHc * HDc);
        const bf16_t* k1 = k0 + 16 * (KVHc * HDc);
#pragma unroll
        for (int c = 0; c < 4; c++) {
            bf16x8 kf = *reinterpret_cast<const bf16x8*>(k0 + c * 32);
            s0 = __builtin_amdgcn_mfma_f32_16x16x32_bf16(qf[c], kf, s0, 0, 0, 0);
        }
#pragma unroll
        for (int c = 0; c < 4; c++) {
            bf16x8 kf = *reinterpret_cast<const bf16x8*>(k1 + c * 32);
            s1 = __builtin_amdgcn_mfma_f32_16x16x32_bf16(qf[c], kf, s1, 0, 0, 0);
        }
        const float scale = 0.08838834764831845f;  // 1/sqrt(128)
        float p0[4], p1[4], alpha[4];
#pragma unroll
        for (int r = 0; r < 4; r++) {
            int i = qb + quad * 4 + r;              // C layout: row = quad*4+reg
            int j0 = kv + l15, j1 = j0 + 16;        // col = lane&15
            float v0 = (j0 <= i && j0 > i - WINc) ? s0[r] * scale : -1e30f;
            float v1 = (j1 <= i && j1 > i - WINc) ? s1[r] * scale : -1e30f;
            float mx = fmaxf(v0, v1);
            mx = fmaxf(mx, __shfl_xor(mx, 1));
            mx = fmaxf(mx, __shfl_xor(mx, 2));
            mx = fmaxf(mx, __shfl_xor(mx, 4));
            mx = fmaxf(mx, __shfl_xor(mx, 8));
            float mnew = fmaxf(m_r[r], mx);
            alpha[r] = __expf(m_r[r] - mnew);
            m_r[r] = mnew;
            p0[r] = __expf(v0 - mnew);
            p1[r] = __expf(v1 - mnew);
            float rs = p0[r] + p1[r];
            rs += __shfl_xor(rs, 1);
            rs += __shfl_xor(rs, 2);
            rs += __shfl_xor(rs, 4);
            rs += __shfl_xor(rs, 8);
            l_r[r] = l_r[r] * alpha[r] + rs;
        }
#pragma unroll
        for (int c = 0; c < 8; c++)
#pragma unroll
            for (int r = 0; r < 4; r++)
                oacc[c][r] *= alpha[r];
        // P: C-layout -> LDS [16 q][32 k] -> A-layout fragment
#pragma unroll
        for (int r = 0; r < 4; r++) {
            Plds[(quad * 4 + r) * 32 + l15]      = (bf16_t)p0[r];
            Plds[(quad * 4 + r) * 32 + 16 + l15] = (bf16_t)p1[r];
        }
        __syncthreads();  // single-wave block: cheap; orders LDS write->read
        bf16x8 pf = *reinterpret_cast<const bf16x8*>(&Plds[l15 * 32 + quad * 8]);
#pragma unroll
        for (int c = 0; c < 8; c++) {
            // B-layout lane: n = dim-in-chunk (l15), k = key (quad*8+j), contiguous in Vt
            bf16x8 vf = *reinterpret_cast<const bf16x8*>(vbase + (size_t)(c * 16 + l15) * Sc + kv + quad * 8);
            oacc[c] = __builtin_amdgcn_mfma_f32_16x16x32_bf16(pf, vf, oacc[c], 0, 0, 0);
        }
        __syncthreads();
    }
    bf16_t* op = O + (size_t)(b * Sc + qb) * DMc + h * HDc;
#pragma unroll
    for (int r = 0; r < 4; r++) {
        float inv = 1.0f / l_r[r];
        int row = quad * 4 + r;
#pragma unroll
        for (int c = 0; c < 8; c++)
            op[(size_t)row * DMc + c * 16 + l15] = (bf16_t)(oacc[c][r] * inv);
    }
}

extern "C" void kernel_launch(void* const* d_in, const int* in_sizes, int n_in,
                              void* d_out, int out_size, void* d_ws, size_t ws_size,
                              hipStream_t stream) {
    const float* hidden = (const float*)d_in[0];
    const float* Wq = (const float*)d_in[1];
    const float* Wk = (const float*)d_in[2];
    const float* Wv = (const float*)d_in[3];
    const float* Wo = (const float*)d_in[4];
    // d_in[5] k_cache, d_in[6] v_cache: scatter-then-gather with identical unique
    // indices is the identity on the attention path -> caches not needed.
    const int* pos = (const int*)d_in[8];
    float* out = (float*)d_out;

    char* ws = (char*)d_ws;
    // 160 MiB layout with reuse:
    bf16_t* Abf  = (bf16_t*)(ws);                 // 32 MiB, reused as attn out
    bf16_t* B1T  = (bf16_t*)(ws + 33554432);      // 48 MiB (WqT|WkT|WvT), reused:
    bf16_t* Qo   = (bf16_t*)(ws + 33554432);      //   32 MiB
    bf16_t* Ko   = (bf16_t*)(ws + 67108864);      //   8 MiB
    bf16_t* Vt   = (bf16_t*)(ws + 75497472);      //   8 MiB
    bf16_t* WoT  = (bf16_t*)(ws + 83886080);      // 32 MiB
    bf16_t* qkv  = (bf16_t*)(ws + 117440512);     // 48 MiB
    bf16_t* attn = Abf;

    dim3 tb(32, 8);
    cast_kernel<<<16384, 256, 0, stream>>>(hidden, Abf, 4194304);
    transpose_cast<<<dim3(128, 128), tb, 0, stream>>>(Wq, B1T, 4096, 4096);
    transpose_cast<<<dim3(32, 128), tb, 0, stream>>>(Wk, B1T + (size_t)4096 * 4096, 4096, 1024);
    transpose_cast<<<dim3(32, 128), tb, 0, stream>>>(Wv, B1T + (size_t)5120 * 4096, 4096, 1024);
    transpose_cast<<<dim3(128, 128), tb, 0, stream>>>(Wo, WoT, 4096, 4096);

    gemm_bt<bf16_t><<<dim3(48, 32), 256, 0, stream>>>(Abf, B1T, qkv, 4096, 6144, 4096);

    rope_kernel<<<dim3(10, 4096), 256, 0, stream>>>(qkv, pos, Qo, Ko);
    vtrans_kernel<<<dim3(32, 4, 32), tb, 0, stream>>>(qkv, Vt);

    attn_kernel<<<8192, 64, 0, stream>>>(Qo, Ko, Vt, attn);

    gemm_bt<float><<<dim3(32, 32), 256, 0, stream>>>(attn, WoT, out, 4096, 4096, 4096);
}

// Round 2
// 900.863 us; speedup vs baseline: 1.1165x; 1.1165x over previous
//
#include <hip/hip_runtime.h>
#include <cstdint>

typedef __bf16 bf16_t;
typedef __attribute__((ext_vector_type(8))) __bf16 bf16x8;
typedef __attribute__((ext_vector_type(4))) __bf16 bf16x4;
typedef __attribute__((ext_vector_type(4))) float f32x4;

typedef __attribute__((address_space(1))) void void_g;
typedef __attribute__((address_space(3))) void void_l;

#define GLDS16(gp, lp) __builtin_amdgcn_global_load_lds( \
    (void_g*)(uintptr_t)(gp), (void_l*)(uintptr_t)(lp), 16, 0, 0)

constexpr int Bc = 4, Sc = 1024, Hc = 32, KVHc = 8, HDc = 128, DMc = 4096;
constexpr int NQ = 6144;     // q|k|v concatenated width
constexpr int WINc = 512;

// ---------------- cast hidden fp32 -> bf16 (vectorized) ----------------
__global__ void cast_kernel(const float* __restrict__ in, bf16_t* __restrict__ out, int n4) {
    int i = blockIdx.x * blockDim.x + threadIdx.x;
    if (i >= n4) return;
    float4 v = reinterpret_cast<const float4*>(in)[i];
    bf16x4 o;
    o[0] = (bf16_t)v.x; o[1] = (bf16_t)v.y; o[2] = (bf16_t)v.z; o[3] = (bf16_t)v.w;
    reinterpret_cast<bf16x4*>(out)[i] = o;
}

// ---------------- cast+transpose: in fp32 [R][C] -> out bf16 [C][R] ----------------
__global__ void transpose_cast(const float* __restrict__ in, bf16_t* __restrict__ out,
                               int R, int C) {
    __shared__ float tile[32][33];
    int c0 = blockIdx.x * 32, r0 = blockIdx.y * 32;
    int tx = threadIdx.x, ty = threadIdx.y;   // (32,8)
    for (int i = 0; i < 32; i += 8)
        tile[ty + i][tx] = in[(size_t)(r0 + ty + i) * C + c0 + tx];
    __syncthreads();
    for (int i = 0; i < 32; i += 8)
        out[(size_t)(c0 + ty + i) * R + r0 + tx] = (bf16_t)tile[tx][ty + i];
}

// ---------------- bf16 MFMA GEMM: C[M][N] = A[M][K] * BT[N][K]^T ----------------
// m97 structure + LDS XOR swizzle (kill 8-way bank conflicts) + group-major
// block order (GROUP_M=8) for L2 locality.
template <typename CT>
__global__ __launch_bounds__(256) void gemm_bt(const bf16_t* __restrict__ A,
                                               const bf16_t* __restrict__ BT,
                                               CT* __restrict__ C,
                                               int M, int N, int K) {
    __shared__ bf16_t As[128 * 32];
    __shared__ bf16_t Bs[128 * 32];
    const int t = threadIdx.x;
    const int lane = t & 63, wave = t >> 6;
    const int wr = wave >> 1, wc = wave & 1;
    const int l15 = lane & 15, quad = lane >> 4;

    // group-major block remap: 8 consecutive M-tiles per N sweep
    const int pid = blockIdx.y * gridDim.x + blockIdx.x;
    const int npn = gridDim.x, npm = gridDim.y;
    const int gsz = 8 * npn;
    const int grp = pid / gsz;
    const int first = grp * 8;
    const int gs = (npm - first) < 8 ? (npm - first) : 8;
    const int pm = first + (pid % gs);
    const int pn = (pid % gsz) / gs;
    const int mBase = pm * 128, nBase = pn * 128;

    const int srow = t >> 2;                                   // 0..63
    const int scol = (((t & 3) ^ ((srow >> 1) & 3)) * 8);      // swizzled k-chunk
    const bf16_t* Ag = A + (size_t)(mBase + srow) * K + scol;
    const bf16_t* Bg = BT + (size_t)(nBase + srow) * K + scol;
    bf16_t* ldsA = &As[wave * 512];
    bf16_t* ldsB = &Bs[wave * 512];

    const int rsw = ((quad ^ ((l15 >> 1) & 3)) * 8);           // read-side swizzle

    f32x4 acc[4][4] = {};

    for (int kk = 0; kk < K; kk += 32) {
        GLDS16(Ag + kk,                  ldsA);
        GLDS16(Ag + kk + (size_t)64 * K, ldsA + 2048);
        GLDS16(Bg + kk,                  ldsB);
        GLDS16(Bg + kk + (size_t)64 * K, ldsB + 2048);
        __syncthreads();
        bf16x8 af[4], bfv[4];
#pragma unroll
        for (int i = 0; i < 4; i++)
            af[i] = *reinterpret_cast<const bf16x8*>(&As[(wr * 64 + i * 16 + l15) * 32 + rsw]);
#pragma unroll
        for (int j = 0; j < 4; j++)
            bfv[j] = *reinterpret_cast<const bf16x8*>(&Bs[(wc * 64 + j * 16 + l15) * 32 + rsw]);
#pragma unroll
        for (int i = 0; i < 4; i++)
#pragma unroll
            for (int j = 0; j < 4; j++)
                acc[i][j] = __builtin_amdgcn_mfma_f32_16x16x32_bf16(af[i], bfv[j], acc[i][j], 0, 0, 0);
        __syncthreads();
    }
#pragma unroll
    for (int i = 0; i < 4; i++) {
        int row0 = mBase + wr * 64 + i * 16 + quad * 4;
#pragma unroll
        for (int j = 0; j < 4; j++) {
            int col = nBase + wc * 64 + j * 16 + l15;
#pragma unroll
            for (int r = 0; r < 4; r++)
                C[(size_t)(row0 + r) * N + col] = (CT)acc[i][j][r];
        }
    }
}

// ---------------- RoPE: qkv bf16 [4096][6144] -> Qo [4096][4096], Ko [4096][1024] ----------------
__global__ void rope_kernel(const bf16_t* __restrict__ qkv, const int* __restrict__ pos,
                            bf16_t* __restrict__ Qo, bf16_t* __restrict__ Ko) {
    int t = blockIdx.y;
    int hd = blockIdx.x * blockDim.x + threadIdx.x;  // 0..2559 (40 heads x 64 pairs)
    int head = hd >> 6, d = hd & 63;
    float p = (float)pos[t];
    float invf = exp2f(-(float)d * (19.931568569324174f / 64.0f));
    float ang = p * invf;
    float sn, cs;
    __sincosf(ang, &sn, &cs);
    const bf16_t* src; bf16_t* dst;
    if (head < 32) {
        src = qkv + (size_t)t * NQ + head * 128 + d;
        dst = Qo + (size_t)t * DMc + head * 128 + d;
    } else {
        int kh = head - 32;
        src = qkv + (size_t)t * NQ + 4096 + kh * 128 + d;
        dst = Ko + (size_t)t * (KVHc * HDc) + kh * 128 + d;
    }
    float x1 = (float)src[0], x2 = (float)src[64];
    dst[0]  = (bf16_t)(x1 * cs - x2 * sn);
    dst[64] = (bf16_t)(x2 * cs + x1 * sn);
}

// ---------------- V transpose: qkv v-part -> Vt [b*KVH][HD][S] ----------------
__global__ void vtrans_kernel(const bf16_t* __restrict__ qkv, bf16_t* __restrict__ Vt) {
    __shared__ bf16_t tile[32][33];
    int bh = blockIdx.z;               // b*8+kvh
    int b = bh >> 3, kvh = bh & 7;
    int s0 = blockIdx.x * 32, d0 = blockIdx.y * 32;
    int tx = threadIdx.x, ty = threadIdx.y;  // (32,8)
    for (int i = 0; i < 32; i += 8)
        tile[ty + i][tx] = qkv[(size_t)(b * Sc + s0 + ty + i) * NQ + 5120 + kvh * 128 + d0 + tx];
    __syncthreads();
    for (int i = 0; i < 32; i += 8)
        Vt[((size_t)bh * 128 + d0 + ty + i) * Sc + s0 + tx] = tile[tx][ty + i];
}

// ---------------- attention: 4 waves/block = 4 heads sharing a kvh group ----------------
// K/V tiles staged to LDS (double-buffered, XOR-swizzled), one barrier/step.
__global__ __launch_bounds__(256) void attn_kernel(const bf16_t* __restrict__ Q,
                                                   const bf16_t* __restrict__ Kk,
                                                   const bf16_t* __restrict__ Vt,
                                                   bf16_t* __restrict__ O) {
    __shared__ bf16_t Ks[2][32 * 128];
    __shared__ bf16_t Vs[2][128 * 32];
    __shared__ bf16_t Plds[4][16 * 32];
    const int bid = blockIdx.x;        // b*512 + kvh*64 + qt
    const int qt = bid & 63;
    const int kvh = (bid >> 6) & 7;
    const int b = bid >> 9;
    const int t = threadIdx.x;
    const int lane = t & 63, w = t >> 6;
    const int h = kvh * 4 + w;
    const int l15 = lane & 15, quad = lane >> 4;
    const int qb = qt * 16;

    // per-wave Q fragment (A-layout)
    bf16x8 qf[4];
    const bf16_t* qp = Q + (size_t)(b * Sc + qb + l15) * DMc + h * HDc + quad * 8;
#pragma unroll
    for (int c = 0; c < 4; c++) qf[c] = *reinterpret_cast<const bf16x8*>(qp + c * 32);

    // staging source offsets (per thread; two 16B granules per matrix)
    // K tile [32 rows][128 d], 16 granules/row, chunk swizzle ^= (row & 7)
    const int kr0 = t >> 4;                                 // rows 0..15 (second: +16)
    const int kc0 = (((t & 15) ^ (kr0 & 7)) * 8);
    const bf16_t* Kbase = Kk + (size_t)(b * Sc) * (KVHc * HDc) + kvh * HDc;
    const size_t kOff0 = (size_t)kr0 * (KVHc * HDc) + kc0;
    const size_t kOff1 = kOff0 + (size_t)16 * (KVHc * HDc);
    // V tile [128 d][32 s], 4 granules/row, chunk swizzle ^= ((d>>1) & 3)
    const int vd0 = t >> 2;                                 // d 0..63 (second: +64)
    const int vc0 = (((t & 3) ^ ((vd0 >> 1) & 3)) * 8);
    const bf16_t* Vbase = Vt + (size_t)(b * KVHc + kvh) * HDc * Sc;
    const size_t vOff0 = (size_t)vd0 * Sc + vc0;
    const size_t vOff1 = vOff0 + (size_t)64 * Sc;

    f32x4 oacc[8] = {};
    float m_r[4], l_r[4];
#pragma unroll
    for (int r = 0; r < 4; r++) { m_r[r] = -1e30f; l_r[r] = 0.f; }

    const int swl = (l15 >> 1) & 3;    // V/P read-granule swizzle
    const int swk = l15 & 7;           // K read-granule swizzle

    int lo = qb - (WINc - 1); if (lo < 0) lo = 0;
    const int kv_lo = lo & ~31;
    const int nsteps = (qb + 16 - kv_lo + 31) / 32;

    // prologue stage into buf 0
    {
        const bf16_t* ks = Kbase + (size_t)kv_lo * (KVHc * HDc);
        GLDS16(ks + kOff0, &Ks[0][w * 512]);
        GLDS16(ks + kOff1, &Ks[0][2048 + w * 512]);
        const bf16_t* vs = Vbase + kv_lo;
        GLDS16(vs + vOff0, &Vs[0][w * 512]);
        GLDS16(vs + vOff1, &Vs[0][2048 + w * 512]);
    }

    int buf = 0;
    for (int s = 0; s < nsteps; s++) {
        const int kv = kv_lo + s * 32;
        __syncthreads();   // staging of buf complete; prior reads of buf^1 done
        if (s + 1 < nsteps) {
            const int nb = buf ^ 1;
            const bf16_t* ks = Kbase + (size_t)(kv + 32) * (KVHc * HDc);
            GLDS16(ks + kOff0, &Ks[nb][w * 512]);
            GLDS16(ks + kOff1, &Ks[nb][2048 + w * 512]);
            const bf16_t* vs = Vbase + kv + 32;
            GLDS16(vs + vOff0, &Vs[nb][w * 512]);
            GLDS16(vs + vOff1, &Vs[nb][2048 + w * 512]);
        }
        // QK^T from LDS
        f32x4 s0 = {}, s1 = {};
#pragma unroll
        for (int c = 0; c < 4; c++) {
            bf16x8 kf = *reinterpret_cast<const bf16x8*>(
                &Ks[buf][l15 * 128 + (((c * 4 + quad) ^ swk) * 8)]);
            s0 = __builtin_amdgcn_mfma_f32_16x16x32_bf16(qf[c], kf, s0, 0, 0, 0);
        }
#pragma unroll
        for (int c = 0; c < 4; c++) {
            bf16x8 kf = *reinterpret_cast<const bf16x8*>(
                &Ks[buf][(16 + l15) * 128 + (((c * 4 + quad) ^ swk) * 8)]);
            s1 = __builtin_amdgcn_mfma_f32_16x16x32_bf16(qf[c], kf, s1, 0, 0, 0);
        }
        const float scale = 0.08838834764831845f;  // 1/sqrt(128)
        const bool interior = (kv + 31 <= qb) && (kv >= qb - 496);
        float p0[4], p1[4], alpha[4];
#pragma unroll
        for (int r = 0; r < 4; r++) {
            float v0, v1;
            if (interior) {
                v0 = s0[r] * scale; v1 = s1[r] * scale;
            } else {
                int i = qb + quad * 4 + r;
                int j0 = kv + l15, j1 = j0 + 16;
                v0 = (j0 <= i && j0 > i - WINc) ? s0[r] * scale : -1e30f;
                v1 = (j1 <= i && j1 > i - WINc) ? s1[r] * scale : -1e30f;
            }
            float mx = fmaxf(v0, v1);
            mx = fmaxf(mx, __shfl_xor(mx, 1));
            mx = fmaxf(mx, __shfl_xor(mx, 2));
            mx = fmaxf(mx, __shfl_xor(mx, 4));
            mx = fmaxf(mx, __shfl_xor(mx, 8));
            float mnew = fmaxf(m_r[r], mx);
            alpha[r] = __expf(m_r[r] - mnew);
            m_r[r] = mnew;
            p0[r] = __expf(v0 - mnew);
            p1[r] = __expf(v1 - mnew);
            float rs = p0[r] + p1[r];
            rs += __shfl_xor(rs, 1);
            rs += __shfl_xor(rs, 2);
            rs += __shfl_xor(rs, 4);
            rs += __shfl_xor(rs, 8);
            l_r[r] = l_r[r] * alpha[r] + rs;
        }
#pragma unroll
        for (int c = 0; c < 8; c++)
#pragma unroll
            for (int r = 0; r < 4; r++)
                oacc[c][r] *= alpha[r];
        // P: C-layout -> LDS (swizzled) -> A-layout fragment (wave-local ordering
        // via compiler-inserted lgkmcnt; no barrier so prefetch stays in flight)
#pragma unroll
        for (int r = 0; r < 4; r++) {
            int row = quad * 4 + r;
            int sw = (row >> 1) & 3;
            int g0 = l15 >> 3, g1 = 2 + (l15 >> 3);
            Plds[w][row * 32 + (((g0 ^ sw) << 3) | (l15 & 7))] = (bf16_t)p0[r];
            Plds[w][row * 32 + (((g1 ^ sw) << 3) | (l15 & 7))] = (bf16_t)p1[r];
        }
        bf16x8 pf = *reinterpret_cast<const bf16x8*>(&Plds[w][l15 * 32 + ((quad ^ swl) * 8)]);
#pragma unroll
        for (int c = 0; c < 8; c++) {
            bf16x8 vf = *reinterpret_cast<const bf16x8*>(
                &Vs[buf][(c * 16 + l15) * 32 + ((quad ^ swl) * 8)]);
            oacc[c] = __builtin_amdgcn_mfma_f32_16x16x32_bf16(pf, vf, oacc[c], 0, 0, 0);
        }
        buf ^= 1;
    }
    bf16_t* op = O + (size_t)(b * Sc + qb) * DMc + h * HDc;
#pragma unroll
    for (int r = 0; r < 4; r++) {
        float inv = 1.0f / l_r[r];
        int row = quad * 4 + r;
#pragma unroll
        for (int c = 0; c < 8; c++)
            op[(size_t)row * DMc + c * 16 + l15] = (bf16_t)(oacc[c][r] * inv);
    }
}

extern "C" void kernel_launch(void* const* d_in, const int* in_sizes, int n_in,
                              void* d_out, int out_size, void* d_ws, size_t ws_size,
                              hipStream_t stream) {
    const float* hidden = (const float*)d_in[0];
    const float* Wq = (const float*)d_in[1];
    const float* Wk = (const float*)d_in[2];
    const float* Wv = (const float*)d_in[3];
    const float* Wo = (const float*)d_in[4];
    const int* pos = (const int*)d_in[8];
    float* out = (float*)d_out;

    char* ws = (char*)d_ws;
    bf16_t* Abf  = (bf16_t*)(ws);                 // 32 MiB, reused as attn out
    bf16_t* B1T  = (bf16_t*)(ws + 33554432);      // 48 MiB (WqT|WkT|WvT), reused:
    bf16_t* Qo   = (bf16_t*)(ws + 33554432);      //   32 MiB
    bf16_t* Ko   = (bf16_t*)(ws + 67108864);      //   8 MiB
    bf16_t* Vt   = (bf16_t*)(ws + 75497472);      //   8 MiB
    bf16_t* WoT  = (bf16_t*)(ws + 83886080);      // 32 MiB
    bf16_t* qkv  = (bf16_t*)(ws + 117440512);     // 48 MiB
    bf16_t* attn = Abf;

    dim3 tb(32, 8);
    cast_kernel<<<16384, 256, 0, stream>>>(hidden, Abf, 4194304);
    transpose_cast<<<dim3(128, 128), tb, 0, stream>>>(Wq, B1T, 4096, 4096);
    transpose_cast<<<dim3(32, 128), tb, 0, stream>>>(Wk, B1T + (size_t)4096 * 4096, 4096, 1024);
    transpose_cast<<<dim3(32, 128), tb, 0, stream>>>(Wv, B1T + (size_t)5120 * 4096, 4096, 1024);
    transpose_cast<<<dim3(128, 128), tb, 0, stream>>>(Wo, WoT, 4096, 4096);

    gemm_bt<bf16_t><<<dim3(48, 32), 256, 0, stream>>>(Abf, B1T, qkv, 4096, 6144, 4096);

    rope_kernel<<<dim3(10, 4096), 256, 0, stream>>>(qkv, pos, Qo, Ko);
    vtrans_kernel<<<dim3(32, 4, 32), tb, 0, stream>>>(qkv, Vt);

    attn_kernel<<<2048, 256, 0, stream>>>(Qo, Ko, Vt, attn);

    gemm_bt<float><<<dim3(32, 32), 256, 0, stream>>>(attn, WoT, out, 4096, 4096, 4096);
}